// Round 1
// baseline (92.385 us; speedup 1.0000x reference)
//
#include <hip/hip_runtime.h>

#define IMG_W 256
#define IMG_H 256
#define GG 4
#define CUT 15.0f
#define LOG2E  1.44269504088896340736f
#define INV2PI 0.15915494309189533577f

// splats appended to LDS per round; max hits per round == BATCH == capacity
#define BATCH 512
#define LSTRIDE 8    // low  entry: {cx,cy,A,B},{C,pr,pg,pb}
#define HSTRIDE 20   // high entry: + {fx0..3},{fy0..3},{w0..3}  (freqs in revolutions)

// Projection. Quadratic coefficients are pre-negated and pre-scaled by log2(e):
//   weight = exp2(A*dx^2 + B*dx*dy + C*dy^2) == exp(-(0.5 q0 dx^2 + q1 dx dy + 0.5 q2 dy^2))
struct Proj { float cx, cy, A, B, C, rad, pr, pg, pb; };

__device__ __forceinline__ Proj project_one(
    const float* __restrict__ mu,   const float* __restrict__ chol,
    const float* __restrict__ feat, const float* __restrict__ opac, int k)
{
    Proj o;
    float2 m = ((const float2*)mu)[k];
    float m0 = tanhf(m.x), m1 = tanhf(m.y);
    o.cx = (m0 + 1.0f) * (0.5f * (float)IMG_W);
    o.cy = (m1 + 1.0f) * (0.5f * (float)IMG_H);

    const float* c = chol + 3*(size_t)k;
    float l1 = c[0] + 0.5f, l2 = c[1], l3 = c[2] + 0.5f;
    float sxx = l1*l1, sxy = l1*l2, syy = l2*l2 + l3*l3;
    float det = sxx*syy - sxy*sxy;
    float inv = 1.0f / det;
    float q0 = syy*inv, q1 = -sxy*inv, q2 = sxx*inv;

    // conservative cull radius from min eigenvalue of [[q0,q1],[q1,q2]]
    float ht = 0.5f*(q0+q2), hd = 0.5f*(q0-q2);
    float lam = fmaxf(ht - sqrtf(hd*hd + q1*q1), 1e-6f);
    o.rad = sqrtf(2.0f*CUT/lam) + 1.0f;

    o.A = -0.5f*q0*LOG2E;
    o.B = -q1*LOG2E;
    o.C = -0.5f*q2*LOG2E;

    float op = opac[k];
    const float* f = feat + 3*(size_t)k;
    o.pr = f[0]*op; o.pg = f[1]*op; o.pb = f[2]*op;
    return o;
}

// One block per 16x16 tile, 1 px/thread. Projection fused into the cull scan;
// survivors staged as full param records in LDS (batched, double-buffered counter:
// reset of the OTHER counter happens in the append phase, giving 2 barriers/round).
__global__ __launch_bounds__(256) void raster_fused(
    const float* __restrict__ low_mu,   const float* __restrict__ low_chol,
    const float* __restrict__ low_feat, const float* __restrict__ low_opac,
    const float* __restrict__ high_mu,  const float* __restrict__ high_chol,
    const float* __restrict__ high_feat,const float* __restrict__ high_opac,
    const float* __restrict__ gfreq,    const float* __restrict__ gweight,
    int nl, int nh, float* __restrict__ out)
{
    __shared__ float s_buf[BATCH * HSTRIDE];   // 40 KiB
    __shared__ int   s_cnt[2];

    const int tid = threadIdx.x;
    const int bx = blockIdx.x & 15, by = blockIdx.x >> 4;
    const float tx0 = bx*16 + 0.5f, ty0 = by*16 + 0.5f;   // first/last pixel centers
    const float tx1 = tx0 + 15.0f,  ty1 = ty0 + 15.0f;
    const int lx = tid & 15, ly = tid >> 4;
    const float px = bx*16 + lx + 0.5f;
    const float py = by*16 + ly + 0.5f;

    float accr = 0.f, accg = 0.f, accb = 0.f;

    if (tid < 2) s_cnt[tid] = 0;
    __syncthreads();

    int par = 0;

    // ---------- phase 1: low-frequency (pure Gaussian) ----------
    for (int base = 0; base < nl; base += BATCH, par ^= 1) {
        if (tid == 0) s_cnt[par ^ 1] = 0;   // for the round after next; 2 barriers away
        #pragma unroll
        for (int u = 0; u < BATCH/256; ++u) {
            int i = base + u*256 + tid;
            if (i < nl) {
                Proj p = project_one(low_mu, low_chol, low_feat, low_opac, i);
                if (p.cx + p.rad >= tx0 && p.cx - p.rad <= tx1 &&
                    p.cy + p.rad >= ty0 && p.cy - p.rad <= ty1) {
                    int slot = atomicAdd(&s_cnt[par], 1);
                    float4* q = (float4*)(s_buf + slot*LSTRIDE);
                    q[0] = make_float4(p.cx, p.cy, p.A, p.B);
                    q[1] = make_float4(p.C,  p.pr, p.pg, p.pb);
                }
            }
        }
        __syncthreads();
        int cnt = s_cnt[par];
        for (int j = 0; j < cnt; ++j) {            // LDS broadcast reads: conflict-free
            const float4* q = (const float4*)(s_buf + j*LSTRIDE);
            float4 a = q[0], b = q[1];
            float dx = px - a.x, dy = py - a.y;
            float s2 = (a.z*dx + a.w*dy)*dx + b.x*dy*dy;
            float e  = __builtin_amdgcn_exp2f(s2);
            accr = fmaf(e, b.y, accr);
            accg = fmaf(e, b.z, accg);
            accb = fmaf(e, b.w, accb);
        }
        __syncthreads();
    }

    // ---------- phase 2: high-frequency (Gabor-modulated) ----------
    for (int base = 0; base < nh; base += BATCH, par ^= 1) {
        if (tid == 0) s_cnt[par ^ 1] = 0;
        #pragma unroll
        for (int u = 0; u < BATCH/256; ++u) {
            int i = base + u*256 + tid;
            if (i < nh) {
                Proj p = project_one(high_mu, high_chol, high_feat, high_opac, i);
                if (p.cx + p.rad >= tx0 && p.cx - p.rad <= tx1 &&
                    p.cy + p.rad >= ty0 && p.cy - p.rad <= ty1) {
                    int slot = atomicAdd(&s_cnt[par], 1);
                    float* q = s_buf + slot*HSTRIDE;
                    ((float4*)q)[0] = make_float4(p.cx, p.cy, p.A, p.B);
                    ((float4*)q)[1] = make_float4(p.C,  p.pr, p.pg, p.pb);
                    #pragma unroll
                    for (int g = 0; g < GG; ++g) {
                        float2 f = ((const float2*)gfreq)[i*GG + g];
                        q[8  + g] = f.x * INV2PI;     // revolutions/pixel
                        q[12 + g] = f.y * INV2PI;
                        q[16 + g] = gweight[i*GG + g];
                    }
                }
            }
        }
        __syncthreads();
        int cnt = s_cnt[par];
        for (int j = 0; j < cnt; ++j) {
            const float* q = s_buf + j*HSTRIDE;
            float4 a = ((const float4*)q)[0], b = ((const float4*)q)[1];
            float dx = px - a.x, dy = py - a.y;
            float s2 = (a.z*dx + a.w*dy)*dx + b.x*dy*dy;
            float e  = __builtin_amdgcn_exp2f(s2);
            float mod = 0.f;
            #pragma unroll
            for (int g = 0; g < GG; ++g) {
                float ph = q[8+g]*dx + q[12+g]*dy;          // revolutions
                float fr = __builtin_amdgcn_fractf(ph);     // v_fract then v_cos
                mod = fmaf(q[16+g], __builtin_amdgcn_cosf(fr), mod);
            }
            float e2 = e * mod;
            accr = fmaf(e2, b.y, accr);
            accg = fmaf(e2, b.z, accg);
            accb = fmaf(e2, b.w, accb);
        }
        __syncthreads();
    }

    // ---------- write clipped planar output (1,3,H,W) ----------
    int x = bx*16 + lx, y = by*16 + ly;
    int pix = y*IMG_W + x;
    out[pix]                 = fminf(fmaxf(accr, 0.f), 1.f);
    out[IMG_H*IMG_W + pix]   = fminf(fmaxf(accg, 0.f), 1.f);
    out[2*IMG_H*IMG_W + pix] = fminf(fmaxf(accb, 0.f), 1.f);
}

extern "C" void kernel_launch(void* const* d_in, const int* in_sizes, int n_in,
                              void* d_out, int out_size, void* d_ws, size_t ws_size,
                              hipStream_t stream)
{
    const float* low_mu    = (const float*)d_in[0];
    const float* high_mu   = (const float*)d_in[1];
    const float* low_chol  = (const float*)d_in[2];
    const float* high_chol = (const float*)d_in[3];
    const float* low_feat  = (const float*)d_in[4];
    const float* high_feat = (const float*)d_in[5];
    const float* low_opac  = (const float*)d_in[6];
    const float* high_opac = (const float*)d_in[7];
    const float* gfreq     = (const float*)d_in[8];
    const float* gweight   = (const float*)d_in[9];

    int nl = in_sizes[0] / 2;
    int nh = in_sizes[1] / 2;

    (void)d_ws; (void)ws_size;   // workspace no longer used: projection fused into raster

    raster_fused<<<256, 256, 0, stream>>>(
        low_mu, low_chol, low_feat, low_opac,
        high_mu, high_chol, high_feat, high_opac,
        gfreq, gweight, nl, nh, (float*)d_out);
}